// Round 4
// baseline (240.840 us; speedup 1.0000x reference)
//
#include <hip/hip_runtime.h>

// Graph2Col: stable stream compaction of (m=128, V=2048, R=32) int32 mapping.
// Valid (!= -1) entries first in row-major order; tail filled with -1.
// Output layout in d_out (int32): nodes_indices [total*2] then column_indices [total*3].
//
// R4: single-pass decoupled-lookback compaction. Input read ONCE into regs.
//     Status flags are poison-proof (0xAA.. top nibble is invalid), so no
//     memset of d_ws is required. Tail fill distributed per-block via each
//     block's own invalid-count slice (no global total needed).

#define EMPTY_V (-1)

constexpr int TOTAL = 8388608;                 // 128*2048*32
constexpr int BLOCK = 256;
constexpr int CHUNK = 16384;                   // elements per block
constexpr int NB = TOTAL / CHUNK;              // 512 blocks (all co-resident @ >=2/CU)
constexpr int SUBT = CHUNK / (BLOCK * 4);      // 16 sub-tiles of 1024 elements
constexpr int NWAVE = BLOCK / 64;              // 4 waves
constexpr int STAGE = BLOCK * 4;               // 1024 entries staged per sub-tile

// status word: top nibble 1=aggregate ready, 2=inclusive prefix ready.
// 0x0... and poison 0xA... both read as invalid. value in low 28 bits.

__global__ __launch_bounds__(BLOCK, 2) void k_fused(const int* __restrict__ in,
                                                    unsigned* __restrict__ status,
                                                    int* __restrict__ out_nodes,
                                                    int* __restrict__ out_cols) {
    const int b = blockIdx.x;
    const int tid = threadIdx.x;
    const int lane = tid & 63, wid = tid >> 6;
    const unsigned long long below = lane ? ((~0ull) >> (64 - lane)) : 0ull;

    // ---- load entire chunk into registers (single HBM read of the input)
    int4 v[SUBT];
    const int4* p = (const int4*)(in + (size_t)b * CHUNK);
#pragma unroll
    for (int s = 0; s < SUBT; ++s) v[s] = p[s * BLOCK + tid];

    // ---- block aggregate count
    int c = 0;
#pragma unroll
    for (int s = 0; s < SUBT; ++s)
        c += (v[s].x != EMPTY_V) + (v[s].y != EMPTY_V) +
             (v[s].z != EMPTY_V) + (v[s].w != EMPTY_V);
    for (int d = 32; d; d >>= 1) c += __shfl_down(c, d, 64);
    __shared__ int ws[NWAVE];
    __shared__ int s_excl;
    if (lane == 0) ws[wid] = c;
    __syncthreads();
    const int agg = ws[0] + ws[1] + ws[2] + ws[3];

    // ---- decoupled lookback (wave 0)
    if (wid == 0) {
        if (b == 0) {
            if (lane == 0) {
                __hip_atomic_store(&status[0], 0x20000000u | (unsigned)agg,
                                   __ATOMIC_RELEASE, __HIP_MEMORY_SCOPE_AGENT);
                s_excl = 0;
            }
        } else {
            if (lane == 0)
                __hip_atomic_store(&status[b], 0x10000000u | (unsigned)agg,
                                   __ATOMIC_RELEASE, __HIP_MEMORY_SCOPE_AGENT);
            int excl = 0, idx = b;
            while (true) {
                const int pb = idx - 1 - lane;
                unsigned st;
                if (pb >= 0) {
                    do {
                        st = __hip_atomic_load(&status[pb], __ATOMIC_ACQUIRE,
                                               __HIP_MEMORY_SCOPE_AGENT);
                    } while ((st >> 28) != 1u && (st >> 28) != 2u);
                } else {
                    st = 0x20000000u;  // virtual block with prefix 0
                }
                const unsigned fl = st >> 28;
                int contrib = (int)(st & 0x0FFFFFFFu);
                const unsigned long long pm = __ballot(fl == 2u);
                if (pm) {
                    const int Lmin = __ffsll((unsigned long long)pm) - 1;
                    if (lane > Lmin) contrib = 0;   // keep AGGs below + the PREFIX
                    for (int d = 32; d; d >>= 1) contrib += __shfl_down(contrib, d, 64);
                    excl += contrib;                 // lane 0 holds the true sum
                    break;
                } else {
                    for (int d = 32; d; d >>= 1) contrib += __shfl_down(contrib, d, 64);
                    excl += contrib;
                    idx -= 64;
                }
            }
            if (lane == 0) {
                __hip_atomic_store(&status[b], 0x20000000u | (unsigned)(excl + agg),
                                   __ATOMIC_RELEASE, __HIP_MEMORY_SCOPE_AGENT);
                s_excl = excl;
            }
        }
    }
    __syncthreads();
    const int excl0 = s_excl;
    int running = excl0;

    // ---- scatter: stage each sub-tile in LDS, stream out coalesced
    __shared__ int wsum[NWAVE];
    __shared__ int s_val[STAGE];
    __shared__ int s_pos[STAGE];   // fi & 65535 (packs vert<<5 | reg)
    const int row = b >> 2;        // 16384 elems/block, 65536 elems/output-row
#pragma unroll
    for (int s = 0; s < SUBT; ++s) {
        const int f0 = (v[s].x != EMPTY_V), f1 = (v[s].y != EMPTY_V);
        const int f2 = (v[s].z != EMPTY_V), f3 = (v[s].w != EMPTY_V);
        const unsigned long long b0 = __ballot(f0), b1 = __ballot(f1);
        const unsigned long long b2 = __ballot(f2), b3 = __ballot(f3);
        const int pre = __popcll(b0 & below) + __popcll(b1 & below) +
                        __popcll(b2 & below) + __popcll(b3 & below);
        const int wtot = __popcll(b0) + __popcll(b1) + __popcll(b2) + __popcll(b3);
        if (lane == 0) wsum[wid] = wtot;
        __syncthreads();
        int woff = 0, cnt = 0;
        for (int w = 0; w < NWAVE; ++w) {
            const int x = wsum[w];
            cnt += x;
            if (w < wid) woff += x;
        }
        int lp = woff + pre;
        const int rem0 = ((b & 3) << 14) + (s << 10) + (tid << 2);  // fi & 65535
        const int vals[4] = {v[s].x, v[s].y, v[s].z, v[s].w};
        const int fl4[4] = {f0, f1, f2, f3};
#pragma unroll
        for (int j = 0; j < 4; ++j) {
            if (fl4[j]) { s_val[lp] = vals[j]; s_pos[lp] = rem0 + j; ++lp; }
        }
        __syncthreads();

        // ---- nodes: int4 stores (2 entries each), peel for 16B alignment
        {
            int2* b2p = (int2*)out_nodes + running;           // 8B units
            const int head = ((running & 1) && cnt > 0) ? 1 : 0;
            if (head && tid == 0) b2p[0] = make_int2(row, s_val[0]);
            const int nPairs = (cnt - head) >> 1;
            int4* b4p = (int4*)(b2p + head);                  // 16B aligned
            for (int k = tid; k < nPairs; k += BLOCK) {
                const int e = head + 2 * k;
                b4p[k] = make_int4(row, s_val[e], row, s_val[e + 1]);
            }
            if (((cnt - head) & 1) && tid == BLOCK - 1)
                b2p[cnt - 1] = make_int2(row, s_val[cnt - 1]);
        }
        // ---- cols: int4 stores (4 dwords each), peel for 16B alignment
        {
            int* cd = out_cols + 3 * (size_t)running;
            const int cdw = 3 * cnt;
            const int mis = (3 * running) & 3;
            int peel = mis ? (4 - mis) : 0;
            if (peel > cdw) peel = cdw;
            if (tid < peel) {
                const int ld = tid;
                const int e = ld / 3, r = ld - 3 * e;
                int vv = row;
                if (r) { const int pp = s_pos[e]; vv = (r == 1) ? (pp >> 5) : (pp & 31); }
                cd[ld] = vv;
            }
            const int body = (cdw - peel) >> 2;
            int4* c4p = (int4*)(cd + peel);                   // 16B aligned
            for (int k = tid; k < body; k += BLOCK) {
                const int ld0 = peel + 4 * k;
                int vv[4];
#pragma unroll
                for (int i = 0; i < 4; ++i) {
                    const int ld = ld0 + i;
                    const int e = ld / 3, r = ld - 3 * e;
                    int x = row;
                    if (r) { const int pp = s_pos[e]; x = (r == 1) ? (pp >> 5) : (pp & 31); }
                    vv[i] = x;
                }
                c4p[k] = make_int4(vv[0], vv[1], vv[2], vv[3]);
            }
            const int tails = cdw - peel - 4 * body;
            if (tid < tails) {
                const int ld = peel + 4 * body + tid;
                const int e = ld / 3, r = ld - 3 * e;
                int vv = row;
                if (r) { const int pp = s_pos[e]; vv = (r == 1) ? (pp >> 5) : (pp & 31); }
                cd[ld] = vv;
            }
        }
        running += cnt;
        __syncthreads();  // protect wsum/s_val/s_pos for next sub-tile
    }

    // ---- tail slice for this block: its own invalid entries, counted from end.
    // invalid prefix before b = b*CHUNK - excl0 ; this block's invalids = CHUNK - agg.
    {
        const int inv_pref = b * CHUNK - excl0;
        const int start = TOTAL - inv_pref - (CHUNK - agg);
        const int end = TOTAL - inv_pref;
        for (int pos = start + tid; pos < end; pos += BLOCK) {
            out_nodes[2 * pos]     = EMPTY_V;
            out_nodes[2 * pos + 1] = EMPTY_V;
            out_cols[3 * pos]      = EMPTY_V;
            out_cols[3 * pos + 1]  = EMPTY_V;
            out_cols[3 * pos + 2]  = EMPTY_V;
        }
    }
}

extern "C" void kernel_launch(void* const* d_in, const int* in_sizes, int n_in,
                              void* d_out, int out_size, void* d_ws, size_t ws_size,
                              hipStream_t stream) {
    const int* in = (const int*)d_in[0];
    int* out = (int*)d_out;
    int* out_nodes = out;                    // [TOTAL, 2] int32
    int* out_cols = out + 2 * (size_t)TOTAL; // [TOTAL, 3] int32
    unsigned* status = (unsigned*)d_ws;      // [NB] poison-proof status words

    k_fused<<<NB, BLOCK, 0, stream>>>(in, status, out_nodes, out_cols);
}

// Round 6
// 200.909 us; speedup vs baseline: 1.1987x; 1.1987x over previous
//
#include <hip/hip_runtime.h>

// Graph2Col: stable stream compaction of (m=128, V=2048, R=32) int32 mapping.
// Valid (!= -1) entries first in row-major order; tail filled with -1.
// Output layout in d_out (int32): nodes_indices [total*2] then column_indices [total*3].
//
// R6 = R5 with compile fix: nontemporal stores use a native clang vector type
//     (HIP's int4 is a class; __builtin_nontemporal_store rejects it).
//     Two kernels. Scatter stages the WHOLE 4096-elem chunk in 32KB LDS with
//     only 2 barriers/block, XOR-swizzled staging (kills 4-way bank
//     conflicts), nontemporal int4 writeout. Block-local redundant scan of
//     counts[]; tail fill fused (each block owns its own invalid slice).

#define EMPTY_V (-1)

typedef int v4i __attribute__((ext_vector_type(4)));

constexpr int TOTAL = 8388608;                 // 128*2048*32
constexpr int BLOCK = 256;
constexpr int CHUNK = 4096;                    // elements per block
constexpr int NB = TOTAL / CHUNK;              // 2048 blocks
constexpr int SUBT = CHUNK / (BLOCK * 4);      // 4 sub-tiles of 1024 elements
constexpr int NWAVE = BLOCK / 64;              // 4 waves

// LDS staging swizzle: breaks stride-4 write conflicts, keeps reads ~clean
__device__ __forceinline__ int SW(int i) { return i ^ ((i >> 5) & 3); }

// ---------------------------------------------------------------- count pass
__global__ __launch_bounds__(BLOCK) void k_count(const int* __restrict__ in,
                                                 int* __restrict__ counts) {
    const int b = blockIdx.x;
    const int tid = threadIdx.x;
    const int4* p = (const int4*)(in + (size_t)b * CHUNK);
    int c = 0;
#pragma unroll
    for (int s = 0; s < SUBT; ++s) {
        int4 v = p[s * BLOCK + tid];
        c += (v.x != EMPTY_V) + (v.y != EMPTY_V) + (v.z != EMPTY_V) + (v.w != EMPTY_V);
    }
    for (int d = 32; d; d >>= 1) c += __shfl_down(c, d, 64);
    __shared__ int ws[NWAVE];
    const int lane = tid & 63, wid = tid >> 6;
    if (lane == 0) ws[wid] = c;
    __syncthreads();
    if (tid == 0) counts[b] = ws[0] + ws[1] + ws[2] + ws[3];
}

// ---------------------- scatter: scan + stage-whole-chunk + writeout + tail
__global__ __launch_bounds__(BLOCK) void k_scatter(const int* __restrict__ in,
                                                   const int* __restrict__ counts,
                                                   int* __restrict__ out_nodes,
                                                   int* __restrict__ out_cols) {
    const int b = blockIdx.x;
    const int tid = threadIdx.x;
    const int lane = tid & 63, wid = tid >> 6;
    const unsigned long long below = lane ? ((~0ull) >> (64 - lane)) : 0ull;

    __shared__ int red[NWAVE], redt[NWAVE];
    __shared__ int wsum[SUBT * NWAVE];
    __shared__ int s_val[CHUNK];
    __shared__ int s_pos[CHUNK];   // fi & 65535 (packs vert<<5 | reg)

    // ---- per-wave partials of the redundant scan over counts[NB]
    {
        const int4 ca = ((const int4*)counts)[2 * tid];
        const int4 cb = ((const int4*)counts)[2 * tid + 1];
        const int idx0 = tid * 8;
        const int cs[8] = {ca.x, ca.y, ca.z, ca.w, cb.x, cb.y, cb.z, cb.w};
        int pa = 0, ta = 0;
#pragma unroll
        for (int j = 0; j < 8; ++j) {
            ta += cs[j];
            if (idx0 + j < b) pa += cs[j];
        }
        for (int d = 32; d; d >>= 1) {
            pa += __shfl_down(pa, d, 64);
            ta += __shfl_down(ta, d, 64);
        }
        if (lane == 0) { red[wid] = pa; redt[wid] = ta; }
    }

    // ---- load chunk, ballots for all sub-tiles, publish per-wave totals
    int4 v[SUBT];
    int pre[SUBT];
    const int4* p = (const int4*)(in + (size_t)b * CHUNK);
#pragma unroll
    for (int s = 0; s < SUBT; ++s) {
        v[s] = p[s * BLOCK + tid];
        const unsigned long long b0 = __ballot(v[s].x != EMPTY_V);
        const unsigned long long b1 = __ballot(v[s].y != EMPTY_V);
        const unsigned long long b2 = __ballot(v[s].z != EMPTY_V);
        const unsigned long long b3 = __ballot(v[s].w != EMPTY_V);
        pre[s] = __popcll(b0 & below) + __popcll(b1 & below) +
                 __popcll(b2 & below) + __popcll(b3 & below);
        if (lane == 0)
            wsum[s * NWAVE + wid] =
                __popcll(b0) + __popcll(b1) + __popcll(b2) + __popcll(b3);
    }
    __syncthreads();   // barrier 1 of 2

    // ---- scan result + sub-tile bases (all threads, from LDS)
    const int excl = red[0] + red[1] + red[2] + red[3];
    int myoff[SUBT];
    int acc = 0;
#pragma unroll
    for (int s = 0; s < SUBT; ++s) {
        int cs_ = 0, woff = 0;
#pragma unroll
        for (int w = 0; w < NWAVE; ++w) {
            const int x = wsum[s * NWAVE + w];
            cs_ += x;
            if (w < wid) woff += x;
        }
        myoff[s] = acc + woff + pre[s];
        acc += cs_;
    }
    const int blockValid = acc;

    // ---- stage whole chunk (swizzled, conflict-free)
#pragma unroll
    for (int s = 0; s < SUBT; ++s) {
        int lp = myoff[s];
        const int rem0 = ((b & 15) << 12) + (s << 10) + (tid << 2);  // fi & 65535
        const int vals[4] = {v[s].x, v[s].y, v[s].z, v[s].w};
#pragma unroll
        for (int j = 0; j < 4; ++j) {
            if (vals[j] != EMPTY_V) {
                s_val[SW(lp)] = vals[j];
                s_pos[SW(lp)] = rem0 + j;
                ++lp;
            }
        }
    }
    __syncthreads();   // barrier 2 of 2

    const int row = b >> 4;        // 4096 elems/block, 65536 elems/output-row
    const int cnt = blockValid;

    // ---- nodes: int4 nontemporal stores (2 entries each), peel for 16B align
    {
        int2* b2p = (int2*)out_nodes + excl;              // 8B units, 8B aligned
        const int head = ((excl & 1) && cnt > 0) ? 1 : 0;
        if (head && tid == 0) b2p[0] = make_int2(row, s_val[SW(0)]);
        const int nPairs = (cnt - head) >> 1;
        v4i* b4p = (v4i*)(b2p + head);                    // 16B aligned
        for (int k = tid; k < nPairs; k += BLOCK) {
            const int e = head + 2 * k;
            v4i t = {row, s_val[SW(e)], row, s_val[SW(e + 1)]};
            __builtin_nontemporal_store(t, &b4p[k]);
        }
        if (((cnt - head) & 1) && tid == BLOCK - 1)
            b2p[cnt - 1] = make_int2(row, s_val[SW(cnt - 1)]);
    }
    // ---- cols: int4 nontemporal stores (4 dwords each), peel for 16B align
    {
        int* cd = out_cols + 3 * (size_t)excl;
        const int cdw = 3 * cnt;
        const int mis = (3 * excl) & 3;
        int peel = mis ? (4 - mis) : 0;
        if (peel > cdw) peel = cdw;
        if (tid < peel) {
            const int ld = tid;
            const int e = ld / 3, r = ld - 3 * e;
            int vv = row;
            if (r) { const int pp = s_pos[SW(e)]; vv = (r == 1) ? (pp >> 5) : (pp & 31); }
            cd[ld] = vv;
        }
        const int body = (cdw - peel) >> 2;
        v4i* c4p = (v4i*)(cd + peel);                     // 16B aligned
        for (int k = tid; k < body; k += BLOCK) {
            const int ld0 = peel + 4 * k;
            int vv[4];
#pragma unroll
            for (int i = 0; i < 4; ++i) {
                const int ld = ld0 + i;
                const int e = ld / 3, r = ld - 3 * e;
                int x = row;
                if (r) { const int pp = s_pos[SW(e)]; x = (r == 1) ? (pp >> 5) : (pp & 31); }
                vv[i] = x;
            }
            v4i t = {vv[0], vv[1], vv[2], vv[3]};
            __builtin_nontemporal_store(t, &c4p[k]);
        }
        const int tails = cdw - peel - 4 * body;
        if (tid < tails) {
            const int ld = peel + 4 * body + tid;
            const int e = ld / 3, r = ld - 3 * e;
            int vv = row;
            if (r) { const int pp = s_pos[SW(e)]; vv = (r == 1) ? (pp >> 5) : (pp & 31); }
            cd[ld] = vv;
        }
    }

    // ---- tail: this block's invalid entries, counted from the end.
    {
        const int inv_pref = b * CHUNK - excl;            // invalids before this block
        const int start = TOTAL - inv_pref - (CHUNK - blockValid);
        const int end = TOTAL - inv_pref;
        for (int pos = start + tid; pos < end; pos += BLOCK) {
            out_nodes[2 * pos]     = EMPTY_V;
            out_nodes[2 * pos + 1] = EMPTY_V;
            out_cols[3 * pos]      = EMPTY_V;
            out_cols[3 * pos + 1]  = EMPTY_V;
            out_cols[3 * pos + 2]  = EMPTY_V;
        }
    }
}

extern "C" void kernel_launch(void* const* d_in, const int* in_sizes, int n_in,
                              void* d_out, int out_size, void* d_ws, size_t ws_size,
                              hipStream_t stream) {
    const int* in = (const int*)d_in[0];
    int* out = (int*)d_out;
    int* out_nodes = out;                    // [TOTAL, 2] int32
    int* out_cols = out + 2 * (size_t)TOTAL; // [TOTAL, 3] int32
    int* counts = (int*)d_ws;                // [NB]

    k_count<<<NB, BLOCK, 0, stream>>>(in, counts);
    k_scatter<<<NB, BLOCK, 0, stream>>>(in, counts, out_nodes, out_cols);
}

// Round 7
// 189.225 us; speedup vs baseline: 1.2728x; 1.0618x over previous
//
#include <hip/hip_runtime.h>

// Graph2Col: stable stream compaction of (m=128, V=2048, R=32) int32 mapping.
// Valid (!= -1) entries first in row-major order; tail filled with -1.
// Output layout in d_out (int32): nodes_indices [total*2] then column_indices [total*3].
//
// R7: two kernels, whole-chunk LDS staging of the FINAL output dwords
//     (s_nodes[2*CHUNK] + s_cols[3*CHUNK] = 40 KB -> 4 blocks/CU). Writeout is
//     a pure dense LDS->global copy (no per-dword div/swizzle/select). Plain
//     int4 stores (R6's nontemporal suspected regression removed). Block-local
//     redundant scan of counts[]; tail fill fused per-block.

#define EMPTY_V (-1)

typedef int v4i __attribute__((ext_vector_type(4)));

constexpr int TOTAL = 8388608;                 // 128*2048*32
constexpr int BLOCK = 256;
constexpr int CHUNK = 2048;                    // elements per block
constexpr int NB = TOTAL / CHUNK;              // 4096 blocks
constexpr int SUBT = CHUNK / (BLOCK * 4);      // 2 sub-tiles of 1024 elements
constexpr int NWAVE = BLOCK / 64;              // 4 waves

// ---------------------------------------------------------------- count pass
__global__ __launch_bounds__(BLOCK) void k_count(const int* __restrict__ in,
                                                 int* __restrict__ counts) {
    const int b = blockIdx.x;
    const int tid = threadIdx.x;
    const int4* p = (const int4*)(in + (size_t)b * CHUNK);
    int c = 0;
#pragma unroll
    for (int s = 0; s < SUBT; ++s) {
        int4 v = p[s * BLOCK + tid];
        c += (v.x != EMPTY_V) + (v.y != EMPTY_V) + (v.z != EMPTY_V) + (v.w != EMPTY_V);
    }
    for (int d = 32; d; d >>= 1) c += __shfl_down(c, d, 64);
    __shared__ int ws[NWAVE];
    const int lane = tid & 63, wid = tid >> 6;
    if (lane == 0) ws[wid] = c;
    __syncthreads();
    if (tid == 0) counts[b] = ws[0] + ws[1] + ws[2] + ws[3];
}

// dense dword copy LDS -> global with 16B-alignment peel, plain stores
__device__ __forceinline__ void copy_out(int* __restrict__ dst,
                                         const int* __restrict__ src,
                                         int ndw, int tid) {
    const int mis = (int)(((uintptr_t)dst >> 2) & 3);
    int peel = mis ? (4 - mis) : 0;
    if (peel > ndw) peel = ndw;
    if (tid < peel) dst[tid] = src[tid];
    const int body = (ndw - peel) >> 2;
    v4i* d4 = (v4i*)(dst + peel);
    const int* s4 = src + peel;
    for (int k = tid; k < body; k += BLOCK) {
        v4i t = {s4[4 * k], s4[4 * k + 1], s4[4 * k + 2], s4[4 * k + 3]};
        d4[k] = t;
    }
    const int tails = ndw - peel - 4 * body;
    if (tid < tails) {
        const int ld = peel + 4 * body + tid;
        dst[ld] = src[ld];
    }
}

// ---------------------- scatter: scan + stage final dwords + copyout + tail
__global__ __launch_bounds__(BLOCK) void k_scatter(const int* __restrict__ in,
                                                   const int* __restrict__ counts,
                                                   int* __restrict__ out_nodes,
                                                   int* __restrict__ out_cols) {
    const int b = blockIdx.x;
    const int tid = threadIdx.x;
    const int lane = tid & 63, wid = tid >> 6;
    const unsigned long long below = lane ? ((~0ull) >> (64 - lane)) : 0ull;

    __shared__ int s_nodes[2 * CHUNK];   // 16 KB  (head 48 B doubles as scratch)
    __shared__ int s_cols[3 * CHUNK];    // 24 KB
    int* RED = s_nodes;                  // [NWAVE]      scan partials
    int* WSUM = s_nodes + NWAVE;         // [SUBT*NWAVE] per-subtile wave totals

    // ---- per-wave partials of the redundant scan over counts[NB]
    {
        int pa = 0;
        const int idx0 = tid * 16;
#pragma unroll
        for (int q = 0; q < 4; ++q) {
            const int4 c4 = ((const int4*)counts)[4 * tid + q];
            const int cs[4] = {c4.x, c4.y, c4.z, c4.w};
#pragma unroll
            for (int j = 0; j < 4; ++j)
                if (idx0 + 4 * q + j < b) pa += cs[j];
        }
        for (int d = 32; d; d >>= 1) pa += __shfl_down(pa, d, 64);
        if (lane == 0) RED[wid] = pa;
    }

    // ---- load chunk, ballots, publish per-wave totals
    int4 v[SUBT];
    int pre[SUBT];
    const int4* p = (const int4*)(in + (size_t)b * CHUNK);
#pragma unroll
    for (int s = 0; s < SUBT; ++s) {
        v[s] = p[s * BLOCK + tid];
        const unsigned long long b0 = __ballot(v[s].x != EMPTY_V);
        const unsigned long long b1 = __ballot(v[s].y != EMPTY_V);
        const unsigned long long b2 = __ballot(v[s].z != EMPTY_V);
        const unsigned long long b3 = __ballot(v[s].w != EMPTY_V);
        pre[s] = __popcll(b0 & below) + __popcll(b1 & below) +
                 __popcll(b2 & below) + __popcll(b3 & below);
        if (lane == 0)
            WSUM[s * NWAVE + wid] =
                __popcll(b0) + __popcll(b1) + __popcll(b2) + __popcll(b3);
    }
    __syncthreads();   // barrier 1: RED/WSUM visible

    // ---- read scan results into registers (scratch freed after barrier 2)
    const int excl = RED[0] + RED[1] + RED[2] + RED[3];
    int myoff[SUBT];
    int acc = 0;
#pragma unroll
    for (int s = 0; s < SUBT; ++s) {
        int cs_ = 0, woff = 0;
#pragma unroll
        for (int w = 0; w < NWAVE; ++w) {
            const int x = WSUM[s * NWAVE + w];
            cs_ += x;
            if (w < wid) woff += x;
        }
        myoff[s] = acc + woff + pre[s];
        acc += cs_;
    }
    const int blockValid = acc;
    __syncthreads();   // barrier 2: scratch consumed, staging may overwrite

    // ---- stage final output dwords at compacted local ranks
    const int row = b >> 5;        // 2048 elems/block, 65536 elems/output-row
#pragma unroll
    for (int s = 0; s < SUBT; ++s) {
        int lp = myoff[s];
        const int rem0 = ((b & 31) << 11) + (s << 10) + (tid << 2);  // fi & 65535
        const int vals[4] = {v[s].x, v[s].y, v[s].z, v[s].w};
#pragma unroll
        for (int j = 0; j < 4; ++j) {
            if (vals[j] != EMPTY_V) {
                const int pp = rem0 + j;
                s_nodes[2 * lp] = row;
                s_nodes[2 * lp + 1] = vals[j];
                s_cols[3 * lp] = row;
                s_cols[3 * lp + 1] = pp >> 5;
                s_cols[3 * lp + 2] = pp & 31;
                ++lp;
            }
        }
    }
    __syncthreads();   // barrier 3: staging complete

    // ---- dense copy-out (pure streaming, no per-dword arithmetic)
    copy_out(out_nodes + 2 * (size_t)excl, s_nodes, 2 * blockValid, tid);
    copy_out(out_cols + 3 * (size_t)excl, s_cols, 3 * blockValid, tid);

    // ---- tail: this block's invalid entries, counted from the end.
    {
        const int inv_pref = b * CHUNK - excl;            // invalids before this block
        const int start = TOTAL - inv_pref - (CHUNK - blockValid);
        const int end = TOTAL - inv_pref;
        for (int pos = start + tid; pos < end; pos += BLOCK) {
            out_nodes[2 * pos]     = EMPTY_V;
            out_nodes[2 * pos + 1] = EMPTY_V;
            out_cols[3 * pos]      = EMPTY_V;
            out_cols[3 * pos + 1]  = EMPTY_V;
            out_cols[3 * pos + 2]  = EMPTY_V;
        }
    }
}

extern "C" void kernel_launch(void* const* d_in, const int* in_sizes, int n_in,
                              void* d_out, int out_size, void* d_ws, size_t ws_size,
                              hipStream_t stream) {
    const int* in = (const int*)d_in[0];
    int* out = (int*)d_out;
    int* out_nodes = out;                    // [TOTAL, 2] int32
    int* out_cols = out + 2 * (size_t)TOTAL; // [TOTAL, 3] int32
    int* counts = (int*)d_ws;                // [NB]

    k_count<<<NB, BLOCK, 0, stream>>>(in, counts);
    k_scatter<<<NB, BLOCK, 0, stream>>>(in, counts, out_nodes, out_cols);
}